// Round 1
// baseline (1475.680 us; speedup 1.0000x reference)
//
#include <hip/hip_runtime.h>
#include <math.h>

// ---------------- workspace layout (floats) ----------------
// [0 .. 17,981,440)      y2 (2048x20x439)          later: logQKV (3x6144x324 = 5,971,968)
// [17,981,440 .. +5.97M) qkv (3x6144x324)          later: mixed (1,990,656) + logO (1,990,656)
// [23,953,408 .. +1052)  stats
#define OFF_Y2   0
#define OFF_QKV  17981440
#define OFF_LOGO (17981440 + 1990656)
#define OFF_ST   (17981440 + 5971968)
// stats offsets
#define ST_SX   0
#define ST_SXX  22
#define ST_WF   506
#define ST_BF   990
#define ST_Y2S  1012
#define ST_Y2Q  1032
#define ST_TOT  1052

#define LOGEPS -9.210340371976182f

// ---------------- K0: zero stats ----------------
__global__ __launch_bounds__(256) void k0_zero(float* __restrict__ st){
  for (int i = threadIdx.x; i < ST_TOT; i += 256) st[i] = 0.f;
}

// ---------------- K1: x second moments (for closed-form BN1 stats) ----------------
__global__ __launch_bounds__(256) void k1_xstats(const float* __restrict__ x, float* __restrict__ st){
  __shared__ __align__(16) float xs[22*444];
  const float* xb = x + (size_t)blockIdx.x * (22*438);
  for (int i = threadIdx.x; i < 22*444; i += 256){
    int h = i / 444, w = i - h*444;
    xs[i] = (w < 438) ? xb[h*438 + w] : 0.f;
  }
  __syncthreads();
  for (int t = threadIdx.x; t < 275; t += 256){
    if (t < 22){
      const float4* r = (const float4*)&xs[t*444];
      float4 acc = {0.f,0.f,0.f,0.f};
      for (int w = 0; w < 111; ++w){ float4 v = r[w]; acc.x+=v.x; acc.y+=v.y; acc.z+=v.z; acc.w+=v.w; }
      atomicAdd(&st[ST_SX + t], acc.x+acc.y+acc.z+acc.w);
    } else {
      int rem = t - 22, h = 0;
      while (rem >= 22 - h){ rem -= 22 - h; ++h; }
      int h2 = h + rem;
      const float4* ra = (const float4*)&xs[h*444];
      const float4* rb = (const float4*)&xs[h2*444];
      float4 acc = {0.f,0.f,0.f,0.f};
      for (int w = 0; w < 111; ++w){
        float4 a = ra[w], b = rb[w];
        acc.x = fmaf(a.x,b.x,acc.x); acc.y = fmaf(a.y,b.y,acc.y);
        acc.z = fmaf(a.z,b.z,acc.z); acc.w = fmaf(a.w,b.w,acc.w);
      }
      atomicAdd(&st[ST_SXX + h*22 + h2], acc.x+acc.y+acc.z+acc.w);
    }
  }
}

// ---------------- K1b: fold BN1 into conv1 weights ----------------
__global__ __launch_bounds__(64) void k1b_fold(const float* __restrict__ W1, const float* __restrict__ g1,
                                               const float* __restrict__ be1, float* __restrict__ st){
  int c = threadIdx.x;
  if (c >= 22) return;
  const float invN = 1.f / (2048.f*438.f);
  float mcol[22];
  float mu0 = 0.f;
  for (int h = 0; h < 22; ++h){ mcol[h] = W1[c*22 + h]; mu0 = fmaf(mcol[h], st[ST_SX + h], mu0); }
  mu0 *= invN;
  float qf = 0.f;
  for (int h = 0; h < 22; ++h)
    for (int h2 = h; h2 < 22; ++h2){
      float w = mcol[h]*mcol[h2]*st[ST_SXX + h*22 + h2];
      qf += (h2 == h) ? w : 2.f*w;
    }
  qf *= invN;
  float var = qf - mu0*mu0;
  float a1 = g1[c] * rsqrtf(var + 1e-5f);
  for (int h = 0; h < 22; ++h) st[ST_WF + h*22 + c] = a1 * mcol[h];
  st[ST_BF + c] = be1[c] - a1 * mu0;   // b1 cancels exactly
}

// ---------------- K3: fused conv1+BN1+conv2 (no b2; additive parts cancel downstream) --------
__global__ __launch_bounds__(512) void k3_conv(const float* __restrict__ x, const float* __restrict__ W2,
                                               const float* __restrict__ st, float* __restrict__ y2){
  __shared__ __align__(16) float zs[22*452];   // z1 padded: zs[c][w+6], pads zeroed
  __shared__ __align__(16) float w2s[20*268];
  __shared__ __align__(16) float wfs[22*24];
  __shared__ float bfs[22];
  int tid = threadIdx.x;
  int n = blockIdx.x;
  for (int i = tid; i < 484; i += 512){ int h = i/22, c = i - h*22; wfs[h*24 + c] = st[ST_WF + i]; }
  for (int i = tid; i < 5280; i += 512){ int d = i/264, r = i - d*264; w2s[d*268 + r] = W2[i]; }
  if (tid < 22) bfs[tid] = st[ST_BF + tid];
  for (int i = tid; i < 22*14; i += 512){ int c = i/14, k = i - c*14; int w = (k < 6) ? k : (438 + k); zs[c*452 + w] = 0.f; }
  __syncthreads();
  if (tid < 438){
    float acc[22];
    #pragma unroll
    for (int c = 0; c < 22; ++c) acc[c] = bfs[c];
    const float* xb = x + (size_t)n*(22*438) + tid;
    #pragma unroll 1
    for (int h = 0; h < 22; ++h){
      float xv = xb[h*438];
      #pragma unroll
      for (int c = 0; c < 22; ++c) acc[c] = fmaf(wfs[h*24 + c], xv, acc[c]);
    }
    #pragma unroll
    for (int c = 0; c < 22; ++c) zs[c*452 + tid + 6] = acc[c];
  }
  __syncthreads();
  for (int o = tid; o < 20*55; o += 512){
    int chunk = o / 20, d = o - chunk*20;
    int w0 = chunk*8;
    float acc[8] = {0.f,0.f,0.f,0.f,0.f,0.f,0.f,0.f};
    #pragma unroll 1
    for (int c = 0; c < 22; ++c){
      const float* zr = &zs[c*452 + w0];
      float zw[20];
      #pragma unroll
      for (int k = 0; k < 20; k += 4){ float4 v = *(const float4*)&zr[k]; zw[k]=v.x; zw[k+1]=v.y; zw[k+2]=v.z; zw[k+3]=v.w; }
      const float* wr = &w2s[d*268 + c*12];
      float wt[12];
      #pragma unroll
      for (int t = 0; t < 12; t += 4){ float4 v = *(const float4*)&wr[t]; wt[t]=v.x; wt[t+1]=v.y; wt[t+2]=v.z; wt[t+3]=v.w; }
      #pragma unroll
      for (int jj = 0; jj < 8; ++jj)
        #pragma unroll
        for (int t = 0; t < 12; ++t)
          acc[jj] = fmaf(wt[t], zw[jj+t], acc[jj]);
    }
    float* yb = y2 + (size_t)n*8780 + d*439;
    #pragma unroll
    for (int jj = 0; jj < 8; ++jj){ int w = w0 + jj; if (w < 439) yb[w] = acc[jj]; }
  }
}

// ---------------- K3b: y2 per-channel sum/sumsq (for BN2 scale) ----------------
__global__ __launch_bounds__(256) void k3b_y2stats(const float* __restrict__ y2, float* __restrict__ st){
  int d = blockIdx.x, chunk = blockIdx.y;
  float sum = 0.f, sq = 0.f;
  for (int n = chunk*128; n < chunk*128 + 128; ++n){
    const float* r = y2 + (size_t)n*8780 + d*439;
    for (int w = threadIdx.x; w < 439; w += 256){ float v = r[w]; sum += v; sq = fmaf(v, v, sq); }
  }
  __shared__ float red[4][2];
  for (int off = 32; off; off >>= 1){ sum += __shfl_down(sum, off); sq += __shfl_down(sq, off); }
  int wid = threadIdx.x >> 6;
  if ((threadIdx.x & 63) == 0){ red[wid][0] = sum; red[wid][1] = sq; }
  __syncthreads();
  if (threadIdx.x == 0){
    float s = 0.f, q = 0.f;
    for (int i = 0; i < 4; ++i){ s += red[i][0]; q += red[i][1]; }
    atomicAdd(&st[ST_Y2S + d], s);
    atomicAdd(&st[ST_Y2Q + d], q);
  }
}

// ---------------- K4: per-(n,patch) covariance + Q/K/V congruence ----------------
__global__ __launch_bounds__(256) void k4_cov_qkv(const float* __restrict__ y2, const float* __restrict__ st,
    const float* __restrict__ g2, const float* __restrict__ Wq, const float* __restrict__ Wk,
    const float* __restrict__ Wv, float* __restrict__ qkv){
  __shared__ float ys[20*444];
  __shared__ float a2s[20];
  __shared__ float B[3][360];
  __shared__ float G[400];
  __shared__ float Tm[360];
  __shared__ float musum[20];
  __shared__ float rtr;
  int tid = threadIdx.x, n = blockIdx.x;
  if (tid < 20){
    const float invN = 1.f/(2048.f*439.f);
    float s = st[ST_Y2S + tid]*invN;
    float q = st[ST_Y2Q + tid]*invN;
    a2s[tid] = g2[tid] * rsqrtf(q - s*s + 1e-5f);
  }
  const float* yb = y2 + (size_t)n*8780;
  for (int i = tid; i < 8780; i += 256){ int d = i/439, w = i - d*439; ys[d*444 + w] = yb[i]; }
  __syncthreads();
  for (int i = tid; i < 3*360; i += 256){
    int wt = i/360, r = i - wt*360; int d = r/18;
    const float* Wm = (wt==0) ? Wq : ((wt==1) ? Wk : Wv);
    B[wt][r] = a2s[d]*Wm[r];
  }
  for (int m = 0; m < 3; ++m){
    int off = (m==0) ? 0 : ((m==1) ? 147 : 293);
    int L   = (m==0) ? 147 : 146;
    __syncthreads();
    if (tid < 20){
      float s = 0.f; const float* r = &ys[tid*444 + off];
      for (int w = 0; w < L; ++w) s += r[w];
      musum[tid] = s;
    }
    __syncthreads();
    for (int t = tid; t < 210; t += 256){
      int rem = t, c = 0;
      while (rem >= 20 - c){ rem -= 20 - c; ++c; }
      int d = c + rem;
      const float* ra = &ys[c*444 + off];
      const float* rb = &ys[d*444 + off];
      float acc = 0.f;
      for (int w = 0; w < L; ++w) acc = fmaf(ra[w], rb[w], acc);
      acc -= musum[c]*musum[d]*(1.f/(float)L);
      G[c*20 + d] = acc; G[d*20 + c] = acc;
    }
    __syncthreads();
    if (tid == 0){
      float tr = 0.f;
      for (int c = 0; c < 20; ++c){ float a = a2s[c]; tr = fmaf(a*a, G[c*21], tr); }
      rtr = 1.f/tr;
    }
    __syncthreads();
    for (int wt = 0; wt < 3; ++wt){
      for (int t = tid; t < 360; t += 256){
        int p = t/18, jj = t - p*18;
        float acc = 0.f;
        for (int dd = 0; dd < 20; ++dd) acc = fmaf(G[p*20 + dd], B[wt][dd*18 + jj], acc);
        Tm[t] = acc;
      }
      __syncthreads();
      float* outm = qkv + ((size_t)wt*6144 + (size_t)n*3 + m)*324;
      for (int t = tid; t < 171; t += 256){
        int rem = t, i = 0;
        while (rem >= 18 - i){ rem -= 18 - i; ++i; }
        int jj = i + rem;
        float acc = 0.f;
        for (int p = 0; p < 20; ++p) acc = fmaf(B[wt][p*18 + i], Tm[p*18 + jj], acc);
        acc *= rtr;
        if (i == jj) acc += 1e-5f;
        outm[i*18 + jj] = acc; outm[jj*18 + i] = acc;
      }
      __syncthreads();
    }
  }
}

// ---------------- K5: batched 18x18 symmetric eigh (tournament Jacobi) + f(A) --------
// mode 0: F = U log(S) U^T ; mode 1: F = U max(S, ln 1e-4) U^T
// lane-per-column, 3 matrices per wave, 12 per 256-thread block.
__global__ __launch_bounds__(256) void k5_jacobi(const float* __restrict__ src, float* __restrict__ dst,
                                                 int nmat, int mode){
  __shared__ __align__(16) float stage[12][384];  // per slot: U rows [18][20] + f(lambda)[18] @360
  int tid = threadIdx.x;
  int wave = tid >> 6, lane = tid & 63;
  int g = (lane >= 54) ? 3 : (lane >= 36 ? 2 : (lane >= 18 ? 1 : 0));
  int j = lane - g*18;
  int gb = g*18;
  int slot = wave*3 + ((g < 3) ? g : 0);
  int mat = blockIdx.x*12 + wave*3 + g;
  bool act = (g < 3) && (mat < nmat);

  float a[18], u[18], dj;
  if (act){
    const float* s = src + (size_t)mat*324 + j*18;
    #pragma unroll
    for (int i = 0; i < 18; ++i) a[i] = s[i];
  } else {
    #pragma unroll
    for (int i = 0; i < 18; ++i) a[i] = (i == j) ? 1.f : 0.f;
  }
  #pragma unroll
  for (int i = 0; i < 18; ++i) u[i] = (i == j) ? 1.f : 0.f;
  dj = 0.f;
  #pragma unroll
  for (int i = 0; i < 18; ++i) dj = (i == j) ? a[i] : dj;

  #pragma unroll 1
  for (int sweep = 0; sweep < 8; ++sweep){
    #pragma unroll
    for (int r = 0; r < 17; ++r){
      // partner m and role for this lane (tournament round r)
      int xx = j - 1 - r; if (xx < 0) xx += 17;
      int v = r + 17 - xx; if (v >= 17) v -= 17;
      int m = (j == 0) ? (1 + r) : ((xx == 0) ? 0 : (1 + v));
      bool isp = (j == 0) ? true : ((xx == 0) ? false : (xx <= 8));
      // a_pq: own element a[m], then take the p-lane's copy so both partners agree bitwise
      float apq_own = 0.f;
      #pragma unroll
      for (int k = 0; k < 18; ++k) apq_own = (k == m) ? a[k] : apq_own;
      int plane = (gb + m) & 63;
      float apq = __shfl(apq_own, isp ? ((gb + j) & 63) : plane);
      float pd = __shfl(dj, plane);
      float app = isp ? dj : pd;
      float aqq = isp ? pd : dj;
      // rotation
      float tau = (aqq - app) / (2.f*apq);
      float tt = 1.f / (fabsf(tau) + sqrtf(fmaf(tau, tau, 1.f)));
      float t = (tau >= 0.f) ? tt : -tt;
      if (!(fabsf(apq) > 1e-36f)) t = 0.f;
      float c = rsqrtf(fmaf(t, t, 1.f));
      float s = t*c;
      dj = isp ? fmaf(-t, apq, app) : fmaf(t, apq, aqq);
      // broadcast all 9 (c,s) from each pair's p-lane
      float cb[9], sb[9];
      #pragma unroll
      for (int q2 = 0; q2 < 9; ++q2){
        int pl;
        if (q2 == 0) pl = 0;
        else { int mm = r + q2; if (mm >= 17) mm -= 17; pl = 1 + mm; }
        cb[q2] = __shfl(c, (gb + pl) & 63);
        sb[q2] = __shfl(s, (gb + pl) & 63);
      }
      // row update J^T A (local within own column)
      #pragma unroll
      for (int q2 = 0; q2 < 9; ++q2){
        int pr, qr;
        if (q2 == 0){ pr = 0; qr = 1 + r; }
        else { int aa = r + q2; if (aa >= 17) aa -= 17; pr = 1 + aa;
               int bb = r + 17 - q2; if (bb >= 17) bb -= 17; qr = 1 + bb; }
        float xv = a[pr], yv = a[qr];
        a[pr] = fmaf(cb[q2], xv, -sb[q2]*yv);
        a[qr] = fmaf(sb[q2], xv,  cb[q2]*yv);
      }
      // column update (A J): exchange partner column
      float pa[18];
      #pragma unroll
      for (int k = 0; k < 18; ++k) pa[k] = __shfl(a[k], plane);
      float sgn = isp ? -s : s;
      #pragma unroll
      for (int k = 0; k < 18; ++k) a[k] = fmaf(c, a[k], sgn*pa[k]);
      // eigenvector update U <- U J (U stored as rows: fully local)
      #pragma unroll
      for (int q2 = 0; q2 < 9; ++q2){
        int pr, qr;
        if (q2 == 0){ pr = 0; qr = 1 + r; }
        else { int aa = r + q2; if (aa >= 17) aa -= 17; pr = 1 + aa;
               int bb = r + 17 - q2; if (bb >= 17) bb -= 17; qr = 1 + bb; }
        float xv = u[pr], yv = u[qr];
        u[pr] = fmaf(cb[q2], xv, -sb[q2]*yv);
        u[qr] = fmaf(sb[q2], xv,  cb[q2]*yv);
      }
    }
  }
  // f(lambda) and reconstruction F = U f(S) U^T
  float fl = (mode == 0) ? logf(fmaxf(dj, 1e-12f)) : fmaxf(dj, LOGEPS);
  float* sp = &stage[slot][0];
  if (act){
    #pragma unroll
    for (int k = 0; k < 18; ++k) sp[j*20 + k] = u[k];
    sp[360 + j] = fl;
  }
  __syncthreads();
  if (act){
    float ut[18];
    #pragma unroll
    for (int k = 0; k < 18; ++k) ut[k] = u[k] * sp[360 + k];
    float* orow = dst + (size_t)mat*324 + j*18;
    #pragma unroll
    for (int i = 0; i < 18; ++i){
      const float* ur = &sp[i*20];
      float acc = 0.f;
      #pragma unroll
      for (int k = 0; k < 18; ++k) acc = fmaf(ut[k], ur[k], acc);
      orow[i] = acc;   // F symmetric: row j == col j
    }
  }
}

// ---------------- K6: energies -> scores -> softmax -> mixed ----------------
__global__ __launch_bounds__(128) void k6_attnmix(const float* __restrict__ logs, float* __restrict__ mixed){
  __shared__ float lq[972], lk[972], lv[972];
  __shared__ float en[9], P[9];
  int b = blockIdx.x, tid = threadIdx.x;
  const float* q  = logs + (size_t)b*972;
  const float* k_ = logs + 1990656 + (size_t)b*972;
  const float* v_ = logs + 3981312 + (size_t)b*972;
  for (int i = tid; i < 972; i += 128){ lq[i] = q[i]; lk[i] = k_[i]; lv[i] = v_[i]; }
  if (tid < 9) en[tid] = 0.f;
  __syncthreads();
  float e[9] = {0.f,0.f,0.f,0.f,0.f,0.f,0.f,0.f,0.f};
  for (int x = tid; x < 324; x += 128){
    float q0 = lq[x], q1 = lq[324+x], q2 = lq[648+x];
    float k0 = lk[x], k1 = lk[324+x], k2 = lk[648+x];
    float d;
    d = q0-k0; e[0] = fmaf(d,d,e[0]);
    d = q0-k1; e[1] = fmaf(d,d,e[1]);
    d = q0-k2; e[2] = fmaf(d,d,e[2]);
    d = q1-k0; e[3] = fmaf(d,d,e[3]);
    d = q1-k1; e[4] = fmaf(d,d,e[4]);
    d = q1-k2; e[5] = fmaf(d,d,e[5]);
    d = q2-k0; e[6] = fmaf(d,d,e[6]);
    d = q2-k1; e[7] = fmaf(d,d,e[7]);
    d = q2-k2; e[8] = fmaf(d,d,e[8]);
  }
  #pragma unroll
  for (int p = 0; p < 9; ++p) atomicAdd(&en[p], e[p]);
  __syncthreads();
  if (tid < 3){
    float s0 = 1.f/(1.f + log1pf(en[tid*3+0]));
    float s1 = 1.f/(1.f + log1pf(en[tid*3+1]));
    float s2 = 1.f/(1.f + log1pf(en[tid*3+2]));
    float mx = fmaxf(s0, fmaxf(s1, s2));
    float e0 = expf(s0-mx), e1 = expf(s1-mx), e2 = expf(s2-mx);
    float inv = 1.f/(e0+e1+e2);
    P[tid*3+0] = e0*inv; P[tid*3+1] = e1*inv; P[tid*3+2] = e2*inv;
  }
  __syncthreads();
  float p00=P[0],p01=P[1],p02=P[2],p10=P[3],p11=P[4],p12=P[5],p20=P[6],p21=P[7],p22=P[8];
  float* mb = mixed + (size_t)b*972;
  for (int x = tid; x < 324; x += 128){
    float v0 = lv[x], v1 = lv[324+x], v2 = lv[648+x];
    mb[x]     = p00*v0 + p01*v1 + p02*v2;
    mb[324+x] = p10*v0 + p11*v1 + p12*v2;
    mb[648+x] = p20*v0 + p21*v1 + p22*v2;
  }
}

// ---------------- K8: triu vectorize + GEMV with Wl + bl ----------------
__global__ __launch_bounds__(64) void k8_out(const float* __restrict__ logO, const float* __restrict__ Wl,
                                             const float* __restrict__ bl, float* __restrict__ outp){
  __shared__ int ti[171], tj[171];
  int b = blockIdx.x, tid = threadIdx.x;
  if (tid < 18){
    int base = tid*(37 - tid)/2;
    for (int jj = tid; jj < 18; ++jj){ ti[base + jj - tid] = tid; tj[base + jj - tid] = jj; }
  }
  __syncthreads();
  float a0=0.f, a1=0.f, a2=0.f, a3=0.f;
  for (int f = tid; f < 513; f += 64){
    int m = f/171, r = f - m*171;
    float vv = logO[(size_t)b*972 + m*324 + ti[r]*18 + tj[r]];
    float4 w = *(const float4*)&Wl[f*4];
    a0 = fmaf(vv, w.x, a0); a1 = fmaf(vv, w.y, a1);
    a2 = fmaf(vv, w.z, a2); a3 = fmaf(vv, w.w, a3);
  }
  for (int off = 32; off; off >>= 1){
    a0 += __shfl_down(a0, off); a1 += __shfl_down(a1, off);
    a2 += __shfl_down(a2, off); a3 += __shfl_down(a3, off);
  }
  if (tid == 0){
    float4 r = { a0 + bl[0], a1 + bl[1], a2 + bl[2], a3 + bl[3] };
    *(float4*)&outp[b*4] = r;
  }
}

// ---------------- launcher ----------------
extern "C" void kernel_launch(void* const* d_in, const int* in_sizes, int n_in,
                              void* d_out, int out_size, void* d_ws, size_t ws_size,
                              hipStream_t stream){
  (void)in_sizes; (void)n_in; (void)out_size; (void)ws_size;
  const float* x   = (const float*)d_in[0];
  const float* W1  = (const float*)d_in[1];
  const float* g1  = (const float*)d_in[3];
  const float* be1 = (const float*)d_in[4];
  const float* W2  = (const float*)d_in[5];
  const float* g2  = (const float*)d_in[7];
  const float* Wq  = (const float*)d_in[9];
  const float* Wk  = (const float*)d_in[10];
  const float* Wv  = (const float*)d_in[11];
  const float* Wl  = (const float*)d_in[12];
  const float* bl  = (const float*)d_in[13];
  // (b1, b2, be2 cancel algebraically)
  float* ws    = (float*)d_ws;
  float* y2    = ws + OFF_Y2;
  float* qkv   = ws + OFF_QKV;
  float* logs  = ws + OFF_Y2;    // overlay: y2 dead after k4
  float* mixed = ws + OFF_QKV;   // overlay: qkv dead after k5#1
  float* logO  = ws + OFF_LOGO;
  float* st    = ws + OFF_ST;
  float* outp  = (float*)d_out;

  k0_zero   <<<dim3(1),        dim3(256), 0, stream>>>(st);
  k1_xstats <<<dim3(2048),     dim3(256), 0, stream>>>(x, st);
  k1b_fold  <<<dim3(1),        dim3(64),  0, stream>>>(W1, g1, be1, st);
  k3_conv   <<<dim3(2048),     dim3(512), 0, stream>>>(x, W2, st, y2);
  k3b_y2stats<<<dim3(20,16),   dim3(256), 0, stream>>>(y2, st);
  k4_cov_qkv<<<dim3(2048),     dim3(256), 0, stream>>>(y2, st, g2, Wq, Wk, Wv, qkv);
  k5_jacobi <<<dim3(1536),     dim3(256), 0, stream>>>(qkv, logs, 18432, 0);
  k6_attnmix<<<dim3(2048),     dim3(128), 0, stream>>>(logs, mixed);
  k5_jacobi <<<dim3(512),      dim3(256), 0, stream>>>(mixed, logO, 6144, 1);
  k8_out    <<<dim3(2048),     dim3(64),  0, stream>>>(logO, Wl, bl, outp);
}

// Round 2
// 1015.796 us; speedup vs baseline: 1.4527x; 1.4527x over previous
//
#include <hip/hip_runtime.h>
#include <math.h>

// ---------------- workspace layout (floats) ----------------
#define OFF_Y2   0
#define OFF_QKV  17981440
#define OFF_LOGO (17981440 + 1990656)
#define OFF_ST   (17981440 + 5971968)
// stats offsets
#define ST_SX   0
#define ST_SXX  22
#define ST_WF   506
#define ST_BF   990
#define ST_Y2S  1012
#define ST_Y2Q  1032
#define ST_TOT  1052

#define LOGEPS -9.210340371976182f
#define NSWEEP 6

// ---------------- K0: zero stats ----------------
__global__ __launch_bounds__(256) void k0_zero(float* __restrict__ st){
  for (int i = threadIdx.x; i < ST_TOT; i += 256) st[i] = 0.f;
}

// ---------------- K1: x second moments (for closed-form BN1 stats) ----------------
__global__ __launch_bounds__(256) void k1_xstats(const float* __restrict__ x, float* __restrict__ st){
  __shared__ __align__(16) float xs[22*444];
  const float* xb = x + (size_t)blockIdx.x * (22*438);
  for (int i = threadIdx.x; i < 22*444; i += 256){
    int h = i / 444, w = i - h*444;
    xs[i] = (w < 438) ? xb[h*438 + w] : 0.f;
  }
  __syncthreads();
  for (int t = threadIdx.x; t < 275; t += 256){
    if (t < 22){
      const float4* r = (const float4*)&xs[t*444];
      float4 acc = {0.f,0.f,0.f,0.f};
      for (int w = 0; w < 111; ++w){ float4 v = r[w]; acc.x+=v.x; acc.y+=v.y; acc.z+=v.z; acc.w+=v.w; }
      atomicAdd(&st[ST_SX + t], acc.x+acc.y+acc.z+acc.w);
    } else {
      int rem = t - 22, h = 0;
      while (rem >= 22 - h){ rem -= 22 - h; ++h; }
      int h2 = h + rem;
      const float4* ra = (const float4*)&xs[h*444];
      const float4* rb = (const float4*)&xs[h2*444];
      float4 acc = {0.f,0.f,0.f,0.f};
      for (int w = 0; w < 111; ++w){
        float4 a = ra[w], b = rb[w];
        acc.x = fmaf(a.x,b.x,acc.x); acc.y = fmaf(a.y,b.y,acc.y);
        acc.z = fmaf(a.z,b.z,acc.z); acc.w = fmaf(a.w,b.w,acc.w);
      }
      atomicAdd(&st[ST_SXX + h*22 + h2], acc.x+acc.y+acc.z+acc.w);
    }
  }
}

// ---------------- K1b: fold BN1 into conv1 weights ----------------
__global__ __launch_bounds__(64) void k1b_fold(const float* __restrict__ W1, const float* __restrict__ g1,
                                               const float* __restrict__ be1, float* __restrict__ st){
  int c = threadIdx.x;
  if (c >= 22) return;
  const float invN = 1.f / (2048.f*438.f);
  float mcol[22];
  float mu0 = 0.f;
  for (int h = 0; h < 22; ++h){ mcol[h] = W1[c*22 + h]; mu0 = fmaf(mcol[h], st[ST_SX + h], mu0); }
  mu0 *= invN;
  float qf = 0.f;
  for (int h = 0; h < 22; ++h)
    for (int h2 = h; h2 < 22; ++h2){
      float w = mcol[h]*mcol[h2]*st[ST_SXX + h*22 + h2];
      qf += (h2 == h) ? w : 2.f*w;
    }
  qf *= invN;
  float var = qf - mu0*mu0;
  float a1 = g1[c] * rsqrtf(var + 1e-5f);
  for (int h = 0; h < 22; ++h) st[ST_WF + h*22 + c] = a1 * mcol[h];
  st[ST_BF + c] = be1[c] - a1 * mu0;   // b1 cancels exactly
}

// ---------------- K3: fused conv1+BN1+conv2 ----------------
__global__ __launch_bounds__(512) void k3_conv(const float* __restrict__ x, const float* __restrict__ W2,
                                               const float* __restrict__ st, float* __restrict__ y2){
  __shared__ __align__(16) float zs[22*452];   // z1 padded: zs[c][w+6], pads zeroed
  __shared__ __align__(16) float w2s[20*268];
  __shared__ __align__(16) float wfs[22*24];
  __shared__ float bfs[22];
  int tid = threadIdx.x;
  int n = blockIdx.x;
  for (int i = tid; i < 484; i += 512){ int h = i/22, c = i - h*22; wfs[h*24 + c] = st[ST_WF + i]; }
  for (int i = tid; i < 5280; i += 512){ int d = i/264, r = i - d*264; w2s[d*268 + r] = W2[i]; }
  if (tid < 22) bfs[tid] = st[ST_BF + tid];
  for (int i = tid; i < 22*14; i += 512){ int c = i/14, k = i - c*14; int w = (k < 6) ? k : (438 + k); zs[c*452 + w] = 0.f; }
  __syncthreads();
  if (tid < 438){
    float acc[22];
    #pragma unroll
    for (int c = 0; c < 22; ++c) acc[c] = bfs[c];
    const float* xb = x + (size_t)n*(22*438) + tid;
    #pragma unroll 1
    for (int h = 0; h < 22; ++h){
      float xv = xb[h*438];
      #pragma unroll
      for (int c = 0; c < 22; ++c) acc[c] = fmaf(wfs[h*24 + c], xv, acc[c]);
    }
    #pragma unroll
    for (int c = 0; c < 22; ++c) zs[c*452 + tid + 6] = acc[c];
  }
  __syncthreads();
  for (int o = tid; o < 20*55; o += 512){
    int chunk = o / 20, d = o - chunk*20;
    int w0 = chunk*8;
    float acc[8] = {0.f,0.f,0.f,0.f,0.f,0.f,0.f,0.f};
    #pragma unroll 1
    for (int c = 0; c < 22; ++c){
      const float* zr = &zs[c*452 + w0];
      float zw[20];
      #pragma unroll
      for (int k = 0; k < 20; k += 4){ float4 v = *(const float4*)&zr[k]; zw[k]=v.x; zw[k+1]=v.y; zw[k+2]=v.z; zw[k+3]=v.w; }
      const float* wr = &w2s[d*268 + c*12];
      float wt[12];
      #pragma unroll
      for (int t = 0; t < 12; t += 4){ float4 v = *(const float4*)&wr[t]; wt[t]=v.x; wt[t+1]=v.y; wt[t+2]=v.z; wt[t+3]=v.w; }
      #pragma unroll
      for (int jj = 0; jj < 8; ++jj)
        #pragma unroll
        for (int t = 0; t < 12; ++t)
          acc[jj] = fmaf(wt[t], zw[jj+t], acc[jj]);
    }
    float* yb = y2 + (size_t)n*8780 + d*439;
    #pragma unroll
    for (int jj = 0; jj < 8; ++jj){ int w = w0 + jj; if (w < 439) yb[w] = acc[jj]; }
  }
}

// ---------------- K3b: y2 per-channel sum/sumsq ----------------
__global__ __launch_bounds__(256) void k3b_y2stats(const float* __restrict__ y2, float* __restrict__ st){
  int d = blockIdx.x, chunk = blockIdx.y;
  float sum = 0.f, sq = 0.f;
  for (int n = chunk*128; n < chunk*128 + 128; ++n){
    const float* r = y2 + (size_t)n*8780 + d*439;
    for (int w = threadIdx.x; w < 439; w += 256){ float v = r[w]; sum += v; sq = fmaf(v, v, sq); }
  }
  __shared__ float red[4][2];
  for (int off = 32; off; off >>= 1){ sum += __shfl_down(sum, off); sq += __shfl_down(sq, off); }
  int wid = threadIdx.x >> 6;
  if ((threadIdx.x & 63) == 0){ red[wid][0] = sum; red[wid][1] = sq; }
  __syncthreads();
  if (threadIdx.x == 0){
    float s = 0.f, q = 0.f;
    for (int i = 0; i < 4; ++i){ s += red[i][0]; q += red[i][1]; }
    atomicAdd(&st[ST_Y2S + d], s);
    atomicAdd(&st[ST_Y2Q + d], q);
  }
}

// ---------------- K4: per-(n,patch) covariance + Q/K/V congruence ----------------
__global__ __launch_bounds__(256) void k4_cov_qkv(const float* __restrict__ y2, const float* __restrict__ st,
    const float* __restrict__ g2, const float* __restrict__ Wq, const float* __restrict__ Wk,
    const float* __restrict__ Wv, float* __restrict__ qkv){
  __shared__ float ys[20*444];
  __shared__ float a2s[20];
  __shared__ float B[3][360];
  __shared__ float G[400];
  __shared__ float Tm[360];
  __shared__ float musum[20];
  __shared__ float rtr;
  int tid = threadIdx.x, n = blockIdx.x;
  if (tid < 20){
    const float invN = 1.f/(2048.f*439.f);
    float s = st[ST_Y2S + tid]*invN;
    float q = st[ST_Y2Q + tid]*invN;
    a2s[tid] = g2[tid] * rsqrtf(q - s*s + 1e-5f);
  }
  const float* yb = y2 + (size_t)n*8780;
  for (int i = tid; i < 8780; i += 256){ int d = i/439, w = i - d*439; ys[d*444 + w] = yb[i]; }
  __syncthreads();
  for (int i = tid; i < 3*360; i += 256){
    int wt = i/360, r = i - wt*360; int d = r/18;
    const float* Wm = (wt==0) ? Wq : ((wt==1) ? Wk : Wv);
    B[wt][r] = a2s[d]*Wm[r];
  }
  for (int m = 0; m < 3; ++m){
    int off = (m==0) ? 0 : ((m==1) ? 147 : 293);
    int L   = (m==0) ? 147 : 146;
    __syncthreads();
    if (tid < 20){
      float s = 0.f; const float* r = &ys[tid*444 + off];
      for (int w = 0; w < L; ++w) s += r[w];
      musum[tid] = s;
    }
    __syncthreads();
    for (int t = tid; t < 210; t += 256){
      int rem = t, c = 0;
      while (rem >= 20 - c){ rem -= 20 - c; ++c; }
      int d = c + rem;
      const float* ra = &ys[c*444 + off];
      const float* rb = &ys[d*444 + off];
      float acc = 0.f;
      for (int w = 0; w < L; ++w) acc = fmaf(ra[w], rb[w], acc);
      acc -= musum[c]*musum[d]*(1.f/(float)L);
      G[c*20 + d] = acc; G[d*20 + c] = acc;
    }
    __syncthreads();
    if (tid == 0){
      float tr = 0.f;
      for (int c = 0; c < 20; ++c){ float a = a2s[c]; tr = fmaf(a*a, G[c*21], tr); }
      rtr = 1.f/tr;
    }
    __syncthreads();
    for (int wt = 0; wt < 3; ++wt){
      for (int t = tid; t < 360; t += 256){
        int p = t/18, jj = t - p*18;
        float acc = 0.f;
        for (int dd = 0; dd < 20; ++dd) acc = fmaf(G[p*20 + dd], B[wt][dd*18 + jj], acc);
        Tm[t] = acc;
      }
      __syncthreads();
      float* outm = qkv + ((size_t)wt*6144 + (size_t)n*3 + m)*324;
      for (int t = tid; t < 171; t += 256){
        int rem = t, i = 0;
        while (rem >= 18 - i){ rem -= 18 - i; ++i; }
        int jj = i + rem;
        float acc = 0.f;
        for (int p = 0; p < 20; ++p) acc = fmaf(B[wt][p*18 + i], Tm[p*18 + jj], acc);
        acc *= rtr;
        if (i == jj) acc += 1e-5f;
        outm[i*18 + jj] = acc; outm[jj*18 + i] = acc;
      }
      __syncthreads();
    }
  }
}

// ---------------- K5: batched 18x18 symmetric eigh (tournament Jacobi) + f(A) --------
// mode 0: F = U log(S) U^T ; mode 1: F = U max(S, ln 1e-4) U^T
// lane-per-column, 3 matrices per wave, 12 per 256-thread block.
// launch_bounds(...,4): cap VGPR<=128 -> 4 waves/SIMD (was 136 VGPR -> 3).
__global__ __launch_bounds__(256, 4) void k5_jacobi(const float* __restrict__ src, float* __restrict__ dst,
                                                    int nmat, int mode){
  __shared__ __align__(16) float stage[12][384];  // per slot: U rows [18][20] + f(lambda)[18] @360
  int tid = threadIdx.x;
  int wave = tid >> 6, lane = tid & 63;
  int g = (lane >= 54) ? 3 : (lane >= 36 ? 2 : (lane >= 18 ? 1 : 0));
  int j = lane - g*18;
  int gb = g*18;
  int slot = wave*3 + ((g < 3) ? g : 0);
  int mat = blockIdx.x*12 + wave*3 + g;
  bool act = (g < 3) && (mat < nmat);

  float a[18], u[18], dj;
  if (act){
    const float* s = src + (size_t)mat*324 + j*18;
    #pragma unroll
    for (int i = 0; i < 18; ++i) a[i] = s[i];
  } else {
    #pragma unroll
    for (int i = 0; i < 18; ++i) a[i] = (i == j) ? 1.f : 0.f;
  }
  #pragma unroll
  for (int i = 0; i < 18; ++i) u[i] = (i == j) ? 1.f : 0.f;
  dj = 0.f;
  #pragma unroll
  for (int i = 0; i < 18; ++i) dj = (i == j) ? a[i] : dj;

  #pragma unroll 1
  for (int sweep = 0; sweep < NSWEEP; ++sweep){
    #pragma unroll
    for (int r = 0; r < 17; ++r){
      // partner m and role for this lane (tournament round r)
      int xx = j - 1 - r; if (xx < 0) xx += 17;
      int v = r + 17 - xx; if (v >= 17) v -= 17;
      int m = (j == 0) ? (1 + r) : ((xx == 0) ? 0 : (1 + v));
      bool isp = (j == 0) ? true : ((xx == 0) ? false : (xx <= 8));
      // a_pq: own element a[m]; take the p-lane's copy so both partners agree bitwise
      float apq_own = 0.f;
      #pragma unroll
      for (int k = 0; k < 18; ++k) apq_own = (k == m) ? a[k] : apq_own;
      int plane = (gb + m) & 63;
      float apq = __shfl(apq_own, isp ? ((gb + j) & 63) : plane);
      float pd = __shfl(dj, plane);
      float app = isp ? dj : pd;
      float aqq = isp ? pd : dj;
      // rotation (fast rcp/rsq: Jacobi is self-correcting, c^2+s^2=1 to ~1ulp)
      float tau = (aqq - app) * 0.5f * __builtin_amdgcn_rcpf(apq);
      float tt = __builtin_amdgcn_rcpf(fabsf(tau) + sqrtf(fmaf(tau, tau, 1.f)));
      float t = (tau >= 0.f) ? tt : -tt;
      if (!(fabsf(apq) > 1e-36f)) t = 0.f;
      float c = __builtin_amdgcn_rsqf(fmaf(t, t, 1.f));
      float s = t*c;
      dj = isp ? fmaf(-t, apq, app) : fmaf(t, apq, aqq);
      // fused: broadcast (c,s) per pair + row update (J^T A) + vector update (U J)
      #pragma unroll
      for (int q2 = 0; q2 < 9; ++q2){
        int pl, pr, qr;
        if (q2 == 0){ pl = 0; pr = 0; qr = 1 + r; }
        else { int aa = r + q2; if (aa >= 17) aa -= 17; pl = 1 + aa; pr = pl;
               int bb = r + 17 - q2; if (bb >= 17) bb -= 17; qr = 1 + bb; }
        float cbq = __shfl(c, (gb + pl) & 63);
        float sbq = __shfl(s, (gb + pl) & 63);
        float xv = a[pr], yv = a[qr];
        a[pr] = fmaf(cbq, xv, -sbq*yv);
        a[qr] = fmaf(sbq, xv,  cbq*yv);
        float xu = u[pr], yu = u[qr];
        u[pr] = fmaf(cbq, xu, -sbq*yu);
        u[qr] = fmaf(sbq, xu,  cbq*yu);
      }
      // column update (A J): fused exchange + fma
      float sgn = isp ? -s : s;
      #pragma unroll
      for (int k = 0; k < 18; ++k){
        float pak = __shfl(a[k], plane);
        a[k] = fmaf(c, a[k], sgn*pak);
      }
    }
  }
  // f(lambda) and reconstruction F = U f(S) U^T
  float fl = (mode == 0) ? logf(fmaxf(dj, 1e-12f)) : fmaxf(dj, LOGEPS);
  float* sp = &stage[slot][0];
  if (act){
    #pragma unroll
    for (int k = 0; k < 18; ++k) sp[j*20 + k] = u[k];
    sp[360 + j] = fl;
  }
  __syncthreads();
  if (act){
    float ut[18];
    #pragma unroll
    for (int k = 0; k < 18; ++k) ut[k] = u[k] * sp[360 + k];
    float* orow = dst + (size_t)mat*324 + j*18;
    #pragma unroll
    for (int i = 0; i < 18; ++i){
      const float* ur = &sp[i*20];
      float acc = 0.f;
      #pragma unroll
      for (int k = 0; k < 16; k += 4){
        float4 uv = *(const float4*)&ur[k];
        acc = fmaf(ut[k],   uv.x, acc);
        acc = fmaf(ut[k+1], uv.y, acc);
        acc = fmaf(ut[k+2], uv.z, acc);
        acc = fmaf(ut[k+3], uv.w, acc);
      }
      acc = fmaf(ut[16], ur[16], acc);
      acc = fmaf(ut[17], ur[17], acc);
      orow[i] = acc;   // F symmetric: row j == col j
    }
  }
}

// ---------------- K6: energies -> scores -> softmax -> mixed ----------------
__global__ __launch_bounds__(128) void k6_attnmix(const float* __restrict__ logs, float* __restrict__ mixed){
  __shared__ float lq[972], lk[972], lv[972];
  __shared__ float en[9], P[9];
  int b = blockIdx.x, tid = threadIdx.x;
  const float* q  = logs + (size_t)b*972;
  const float* k_ = logs + 1990656 + (size_t)b*972;
  const float* v_ = logs + 3981312 + (size_t)b*972;
  for (int i = tid; i < 972; i += 128){ lq[i] = q[i]; lk[i] = k_[i]; lv[i] = v_[i]; }
  if (tid < 9) en[tid] = 0.f;
  __syncthreads();
  float e[9] = {0.f,0.f,0.f,0.f,0.f,0.f,0.f,0.f,0.f};
  for (int x = tid; x < 324; x += 128){
    float q0 = lq[x], q1 = lq[324+x], q2 = lq[648+x];
    float k0 = lk[x], k1 = lk[324+x], k2 = lk[648+x];
    float d;
    d = q0-k0; e[0] = fmaf(d,d,e[0]);
    d = q0-k1; e[1] = fmaf(d,d,e[1]);
    d = q0-k2; e[2] = fmaf(d,d,e[2]);
    d = q1-k0; e[3] = fmaf(d,d,e[3]);
    d = q1-k1; e[4] = fmaf(d,d,e[4]);
    d = q1-k2; e[5] = fmaf(d,d,e[5]);
    d = q2-k0; e[6] = fmaf(d,d,e[6]);
    d = q2-k1; e[7] = fmaf(d,d,e[7]);
    d = q2-k2; e[8] = fmaf(d,d,e[8]);
  }
  #pragma unroll
  for (int p = 0; p < 9; ++p) atomicAdd(&en[p], e[p]);
  __syncthreads();
  if (tid < 3){
    float s0 = 1.f/(1.f + log1pf(en[tid*3+0]));
    float s1 = 1.f/(1.f + log1pf(en[tid*3+1]));
    float s2 = 1.f/(1.f + log1pf(en[tid*3+2]));
    float mx = fmaxf(s0, fmaxf(s1, s2));
    float e0 = expf(s0-mx), e1 = expf(s1-mx), e2 = expf(s2-mx);
    float inv = 1.f/(e0+e1+e2);
    P[tid*3+0] = e0*inv; P[tid*3+1] = e1*inv; P[tid*3+2] = e2*inv;
  }
  __syncthreads();
  float p00=P[0],p01=P[1],p02=P[2],p10=P[3],p11=P[4],p12=P[5],p20=P[6],p21=P[7],p22=P[8];
  float* mb = mixed + (size_t)b*972;
  for (int x = tid; x < 324; x += 128){
    float v0 = lv[x], v1 = lv[324+x], v2 = lv[648+x];
    mb[x]     = p00*v0 + p01*v1 + p02*v2;
    mb[324+x] = p10*v0 + p11*v1 + p12*v2;
    mb[648+x] = p20*v0 + p21*v1 + p22*v2;
  }
}

// ---------------- K8: triu vectorize + GEMV with Wl + bl ----------------
__global__ __launch_bounds__(64) void k8_out(const float* __restrict__ logO, const float* __restrict__ Wl,
                                             const float* __restrict__ bl, float* __restrict__ outp){
  __shared__ int ti[171], tj[171];
  int b = blockIdx.x, tid = threadIdx.x;
  if (tid < 18){
    int base = tid*(37 - tid)/2;
    for (int jj = tid; jj < 18; ++jj){ ti[base + jj - tid] = tid; tj[base + jj - tid] = jj; }
  }
  __syncthreads();
  float a0=0.f, a1=0.f, a2=0.f, a3=0.f;
  for (int f = tid; f < 513; f += 64){
    int m = f/171, r = f - m*171;
    float vv = logO[(size_t)b*972 + m*324 + ti[r]*18 + tj[r]];
    float4 w = *(const float4*)&Wl[f*4];
    a0 = fmaf(vv, w.x, a0); a1 = fmaf(vv, w.y, a1);
    a2 = fmaf(vv, w.z, a2); a3 = fmaf(vv, w.w, a3);
  }
  for (int off = 32; off; off >>= 1){
    a0 += __shfl_down(a0, off); a1 += __shfl_down(a1, off);
    a2 += __shfl_down(a2, off); a3 += __shfl_down(a3, off);
  }
  if (tid == 0){
    float4 r = { a0 + bl[0], a1 + bl[1], a2 + bl[2], a3 + bl[3] };
    *(float4*)&outp[b*4] = r;
  }
}

// ---------------- launcher ----------------
extern "C" void kernel_launch(void* const* d_in, const int* in_sizes, int n_in,
                              void* d_out, int out_size, void* d_ws, size_t ws_size,
                              hipStream_t stream){
  (void)in_sizes; (void)n_in; (void)out_size; (void)ws_size;
  const float* x   = (const float*)d_in[0];
  const float* W1  = (const float*)d_in[1];
  const float* g1  = (const float*)d_in[3];
  const float* be1 = (const float*)d_in[4];
  const float* W2  = (const float*)d_in[5];
  const float* g2  = (const float*)d_in[7];
  const float* Wq  = (const float*)d_in[9];
  const float* Wk  = (const float*)d_in[10];
  const float* Wv  = (const float*)d_in[11];
  const float* Wl  = (const float*)d_in[12];
  const float* bl  = (const float*)d_in[13];
  // (b1, b2, be2 cancel algebraically)
  float* ws    = (float*)d_ws;
  float* y2    = ws + OFF_Y2;
  float* qkv   = ws + OFF_QKV;
  float* logs  = ws + OFF_Y2;    // overlay: y2 dead after k4
  float* mixed = ws + OFF_QKV;   // overlay: qkv dead after k5#1
  float* logO  = ws + OFF_LOGO;
  float* st    = ws + OFF_ST;
  float* outp  = (float*)d_out;

  k0_zero   <<<dim3(1),        dim3(256), 0, stream>>>(st);
  k1_xstats <<<dim3(2048),     dim3(256), 0, stream>>>(x, st);
  k1b_fold  <<<dim3(1),        dim3(64),  0, stream>>>(W1, g1, be1, st);
  k3_conv   <<<dim3(2048),     dim3(512), 0, stream>>>(x, W2, st, y2);
  k3b_y2stats<<<dim3(20,16),   dim3(256), 0, stream>>>(y2, st);
  k4_cov_qkv<<<dim3(2048),     dim3(256), 0, stream>>>(y2, st, g2, Wq, Wk, Wv, qkv);
  k5_jacobi <<<dim3(1536),     dim3(256), 0, stream>>>(qkv, logs, 18432, 0);
  k6_attnmix<<<dim3(2048),     dim3(128), 0, stream>>>(logs, mixed);
  k5_jacobi <<<dim3(512),      dim3(256), 0, stream>>>(mixed, logO, 6144, 1);
  k8_out    <<<dim3(2048),     dim3(64),  0, stream>>>(logO, Wl, bl, outp);
}